// Round 4
// baseline (538.684 us; speedup 1.0000x reference)
//
#include <hip/hip_runtime.h>
#include <stdint.h>

// MemoryDiscriminator: embed-GEMM + LeakyReLU + BN(fold into GEMM2) + dual GRU scan + cosine gate.
// Key identities: hm is batch-uniform; only t=T-1 output needed; gi_x hoisted out of scan.
// R4: recurrence -> 16 waves/wg (1024 thr), wave owns ONE 16-col tile across r/z/n (3 MFMA
//     n-tiles, 24 W-frags), 4 gate-elems/lane. 4 waves/SIMD -> MFMA/VALU/LDS pipes overlap
//     across waves instead of phase-locking (R3 showed phases ADD at 2 waves/SIMD).
//     finalize_stats folded into build_wp.

typedef float  f32x4 __attribute__((ext_vector_type(4)));
typedef __bf16 bf16x8 __attribute__((ext_vector_type(8)));

#define B_   256
#define T_   128
#define IN_  128
#define H_   1024
#define OUT_ 256
#define M_   32768   // B*T

// ---------------- workspace layout (bytes) ----------------
static constexpr size_t OFF_XB    = 0;          // 32768*128 bf16   = 8,388,608
static constexpr size_t OFF_WEMB  = 8388608;    // 1024*128 bf16    = 262,144
static constexpr size_t OFF_WHX   = 8650752;    // 768*256 bf16     = 393,216
static constexpr size_t OFF_WHM   = 9043968;    // 768*256 bf16     = 393,216
static constexpr size_t OFF_SUM   = 9437184;    // 1024 f32
static constexpr size_t OFF_SSQ   = 9441280;    // 1024 f32
static constexpr size_t OFF_SCALE = 9445376;    // 1024 f32 (unused, kept for layout)
static constexpr size_t OFF_CC    = 9449472;    // 1024 f32 (unused, kept for layout)
static constexpr size_t OFF_BIASX = 9453568;    // 768 f32 (padded)
static constexpr size_t OFF_GIM   = 9457664;    // 128*768 bf16     = 196,608
static constexpr size_t OFF_EACT  = 9654272;    // 32768*1024 bf16  = 67,108,864
static constexpr size_t OFF_GI    = 76763136;   // 32768*768 bf16   = 50,331,648
static constexpr size_t OFF_HXF   = 127094784;  // 256*256 f32
static constexpr size_t OFF_HMF   = 127356928;  // 16*256 f32
static constexpr size_t OFF_WPX   = 127373312;  // 768*1024 bf16    = 1,572,864
// total ~128.9 MB

__device__ __forceinline__ float sigmoidf_(float x) {
    return __builtin_amdgcn_rcpf(1.0f + __expf(-x));
}
__device__ __forceinline__ float tanhf_(float x) {
    return 1.0f - 2.0f * __builtin_amdgcn_rcpf(1.0f + __expf(2.0f * x));
}
__device__ __forceinline__ void gload_lds16(const void* g, void* l) {
    __builtin_amdgcn_global_load_lds(
        (const __attribute__((address_space(1))) unsigned int*)g,
        (__attribute__((address_space(3))) unsigned int*)l, 16, 0, 0);
}

// ---------------- K0: fp32->bf16 conversions + zero stats ----------------
__global__ void prep(const float* __restrict__ x, const float* __restrict__ wemb,
                     const float* __restrict__ whx, const float* __restrict__ whm,
                     __bf16* __restrict__ xb, __bf16* __restrict__ wembb,
                     __bf16* __restrict__ whxb, __bf16* __restrict__ whmb,
                     float* __restrict__ stats /*2048*/)
{
    long i = (long)blockIdx.x * 256 + threadIdx.x;
    if (i < 2048) stats[i] = 0.0f;
    if (i < 4194304)      xb[i] = (__bf16)x[i];
    else if (i < 4325376) wembb[i - 4194304] = (__bf16)wemb[i - 4194304];
    else if (i < 4521984) whxb[i - 4325376]  = (__bf16)whx[i - 4325376];
    else if (i < 4718592) whmb[i - 4521984]  = (__bf16)whm[i - 4521984];
}

// ---------------- K1/K3: bf16 NT GEMM, 128x128 tile, BK=32, m97-style load_lds staging ----------------
// MODE 0: +bias, LeakyReLU(0.2), store bf16, accumulate per-col sum/sumsq (BN stats)
// MODE 1: +bias, store bf16
template<int MODE>
__launch_bounds__(256)
__global__ void gemm_nt(const __bf16* __restrict__ A, const __bf16* __restrict__ Bm,
                        const float* __restrict__ bias, __bf16* __restrict__ C,
                        float* __restrict__ sums, float* __restrict__ ssqs,
                        int K, int N)
{
    __shared__ __bf16 As[128 * 32];   // unpadded: row stride 32 elems (64 B) -> frag b128 reads at 8-clk floor
    __shared__ __bf16 Bs[128 * 32];   // (global_load_lds requires linear lane order -> no padding allowed)
    const int tid  = threadIdx.x;
    const int lane = tid & 63;
    const int wv   = tid >> 6;
    const int wm   = wv >> 1, wn = wv & 1;
    const int l15  = lane & 15, quad = lane >> 4;
    const long m0 = (long)blockIdx.x * 128;
    const long n0 = (long)blockIdx.y * 128;

    // staging: instr s = wv*2+j writes LDS bytes [s*1024, s*1024+1024); lane covers
    // row s*16 + lane/4, elem cols (lane&3)*8 .. +8  (matches linear lane x 16B order)
    const int srow = lane >> 2;
    const int scol = (lane & 3) * 8;
    const __bf16* ag[2]; const __bf16* bg[2];
    __bf16* al[2]; __bf16* bl[2];
#pragma unroll
    for (int j = 0; j < 2; j++) {
        const int s = wv * 2 + j;
        ag[j] = A  + (m0 + s * 16 + srow) * K + scol;
        bg[j] = Bm + (n0 + s * 16 + srow) * K + scol;
        al[j] = &As[s * 512];
        bl[j] = &Bs[s * 512];
    }

    const f32x4 fz = {0.f, 0.f, 0.f, 0.f};
    f32x4 acc[4][4];
#pragma unroll
    for (int i = 0; i < 4; i++)
#pragma unroll
        for (int j = 0; j < 4; j++) acc[i][j] = fz;

    for (int k0 = 0; k0 < K; k0 += 32) {
        __syncthreads();                      // prior frag reads done before overwrite
        gload_lds16(ag[0] + k0, al[0]);
        gload_lds16(ag[1] + k0, al[1]);
        gload_lds16(bg[0] + k0, bl[0]);
        gload_lds16(bg[1] + k0, bl[1]);
        __syncthreads();                      // drains vmcnt -> tiles ready
        bf16x8 af[4], bfr[4];
#pragma unroll
        for (int mt = 0; mt < 4; mt++)
            af[mt] = *(const bf16x8*)(&As[(wm * 64 + mt * 16 + l15) * 32 + quad * 8]);
#pragma unroll
        for (int nt = 0; nt < 4; nt++)
            bfr[nt] = *(const bf16x8*)(&Bs[(wn * 64 + nt * 16 + l15) * 32 + quad * 8]);
#pragma unroll
        for (int mt = 0; mt < 4; mt++)
#pragma unroll
            for (int nt = 0; nt < 4; nt++)
                acc[mt][nt] = __builtin_amdgcn_mfma_f32_16x16x32_bf16(af[mt], bfr[nt], acc[mt][nt], 0, 0, 0);
    }

#pragma unroll
    for (int nt = 0; nt < 4; nt++) {
        const long ncol = n0 + wn * 64 + nt * 16 + l15;
        const float bi = bias[ncol];
        float s = 0.f, ss = 0.f;
#pragma unroll
        for (int mt = 0; mt < 4; mt++) {
#pragma unroll
            for (int r = 0; r < 4; r++) {
                float v = acc[mt][nt][r] + bi;
                if (MODE == 0) v = (v >= 0.f) ? v : 0.2f * v;
                __bf16 hv = (__bf16)v;
                C[(m0 + wm * 64 + mt * 16 + quad * 4 + r) * (long)N + ncol] = hv;
                if (MODE == 0) { float fv = (float)hv; s += fv; ss += fv * fv; }
            }
        }
        if (MODE == 0) {
            s += __shfl_xor(s, 16);  ss += __shfl_xor(ss, 16);
            s += __shfl_xor(s, 32);  ss += __shfl_xor(ss, 32);
            if (lane < 16) {
                atomicAdd(&sums[n0 + wn * 64 + nt * 16 + lane], s);
                atomicAdd(&ssqs[n0 + wn * 64 + nt * 16 + lane], ss);
            }
        }
    }
}

// ---------------- K2b: stats finalize (inline, redundant per block) + w'_x scale + biasx ----------------
__global__ void build_wp(const float* __restrict__ w_ih_x, const float* __restrict__ b_ih_x,
                         const float* __restrict__ b_hh_x, const float* __restrict__ sums,
                         const float* __restrict__ ssqs, const float* __restrict__ gamma,
                         const float* __restrict__ beta, __bf16* __restrict__ wpx,
                         float* __restrict__ biasx)
{
    const int j = blockIdx.x;      // 768
    const int lane = threadIdx.x;  // 64
    const float inv = 1.0f / 32768.0f;
    float accv = 0.f;
#pragma unroll
    for (int i = 0; i < 16; i++) {
        int h = i * 64 + lane;
        float mean = sums[h] * inv;
        float var  = ssqs[h] * inv - mean * mean;
        float s    = rsqrtf(var + 1e-5f) * gamma[h];
        float c    = beta[h] - mean * s;
        float w = w_ih_x[(long)j * 1024 + h];
        wpx[(long)j * 1024 + h] = (__bf16)(w * s);
        accv += c * w;
    }
    for (int off = 32; off; off >>= 1) accv += __shfl_xor(accv, off);
    if (lane == 0) biasx[j] = accv + b_ih_x[j] + (j < 512 ? b_hh_x[j] : 0.0f);
}

// ---------------- K2c: gi_m[t][j] = memory[t].w_ih_m[j] + b_ih_m + b_hh(r,z) ----------------
__global__ void build_gim(const float* __restrict__ memory, const float* __restrict__ w_ih_m,
                          const float* __restrict__ b_ih_m, const float* __restrict__ b_hh_m,
                          __bf16* __restrict__ gim)
{
    const int j = blockIdx.x;      // 768
    const int t0 = blockIdx.y * 32;
    const int lane = threadIdx.x;  // 64
    float w[16];
#pragma unroll
    for (int i = 0; i < 16; i++) w[i] = w_ih_m[(long)j * 1024 + i * 64 + lane];
    const float bb = b_ih_m[j] + (j < 512 ? b_hh_m[j] : 0.0f);
    for (int t = t0; t < t0 + 32; t++) {
        float s = 0.f;
#pragma unroll
        for (int i = 0; i < 16; i++) s += w[i] * memory[(long)t * 1024 + i * 64 + lane];
        for (int off = 32; off; off >>= 1) s += __shfl_xor(s, off);
        if (lane == 0) gim[t * 768 + j] = (__bf16)(s + bb);
    }
}

// ---------------- K4: GRU recurrence. wg 0..15: 16 batch rows each; wg 16: hm (batch-uniform). ----------------
// 16 waves/wg. Wave v owns cols [16v,16v+16) across gates r/z/n -> 3 MFMA n-tiles, W[3][8] (24 frags,
// AGPR-resident), 4 gate-elems/lane. One barrier/step; gi[t+1] prefetched into double-buffered gil.
__launch_bounds__(1024, 4)
__global__ void recurrence(const __bf16* __restrict__ gi, const __bf16* __restrict__ gim,
                           const __bf16* __restrict__ whx, const __bf16* __restrict__ whm,
                           const float* __restrict__ bhhx, const float* __restrict__ bhhm,
                           float* __restrict__ hxfin, float* __restrict__ hmfin)
{
    __shared__ __bf16 hxl[2][16 * 264];  // [m][k], stride 264 -> ds_read_b128 at floor
    __shared__ __bf16 gil[2][16 * 776];  // row stride 776 elems (1552 B, 16B-aligned, 4-bank skew)
    const int wg   = blockIdx.x;   // 0..16
    const int tid  = threadIdx.x;
    const int lane = tid & 63;
    const int v    = tid >> 6;     // wave 0..15
    const int l15  = lane & 15, quad = lane >> 4;
    const bool isX = (wg < 16);
    const __bf16* wh    = isX ? whx : whm;
    const float*  bhh   = isX ? bhhx : bhhm;
    const __bf16* gbase = isX ? gi : gim;

    // B-frags: wave v owns cols [16v,16v+16) of each gate g=r,z,n (B-row j = g*256 + v*16 + l15)
    bf16x8 W[3][8];
#pragma unroll
    for (int g = 0; g < 3; g++) {
        const long j = g * 256 + v * 16 + l15;
#pragma unroll
        for (int kt = 0; kt < 8; kt++)
            W[g][kt] = *(const bf16x8*)(wh + j * 256 + kt * 32 + quad * 8);
    }
    const int ob = v * 16 + l15;           // owned output column
    const float bhhn = bhh[512 + ob];

    for (int i = tid; i < 16 * 264; i += 1024) hxl[0][i] = (__bf16)0.f;

    float st[4];
#pragma unroll
    for (int i = 0; i < 4; i++) st[i] = 0.f;

    // wave v stages batch-row v of gi[t] (hm wg: same global row replicated to all 16 LDS rows)
    const long grow = isX ? (long)((wg * 16 + v) * 128) * 768 : 0;

    // prefetch gi[0] -> gil[0]
    {
        const __bf16* p = gbase + grow;
        gload_lds16(p + (long)lane * 8, &gil[0][v * 776]);
        if (lane < 32)
            gload_lds16(p + 512 + (long)lane * 8, &gil[0][v * 776 + 512]);
    }
    __syncthreads();   // drains vmcnt (gi[0] staged) + hxl[0] zero-init visible

    int cur = 0;
    for (int t = 0; t < 128; t++) {
        // prefetch gi[t+1] -> gil[(t+1)&1] (other buffer; consumed next step)
        if (t < 127) {
            const __bf16* p = gbase + grow + (long)(t + 1) * 768;
            __bf16* dst = &gil[(t + 1) & 1][v * 776];
            gload_lds16(p + (long)lane * 8, dst);
            if (lane < 32)
                gload_lds16(p + 512 + (long)lane * 8, dst + 512);
        }

        // gh = hx @ w_hh^T for this wave's 3 gate-tiles
        const f32x4 fz = {0.f, 0.f, 0.f, 0.f};
        f32x4 acc[3];
#pragma unroll
        for (int g = 0; g < 3; g++) acc[g] = fz;
        const __bf16* hxc = &hxl[cur][0];
#pragma unroll
        for (int kt = 0; kt < 8; kt++) {
            bf16x8 a = *(const bf16x8*)(hxc + l15 * 264 + kt * 32 + quad * 8);
#pragma unroll
            for (int g = 0; g < 3; g++)
                acc[g] = __builtin_amdgcn_mfma_f32_16x16x32_bf16(a, W[g][kt], acc[g], 0, 0, 0);
        }

        // gate phase: private (acc regs + gil[t&1] staged last step + write other hx buffer)
        const int nxt = cur ^ 1;
        __bf16* hxn = &hxl[nxt][0];
        const __bf16* gcur = &gil[t & 1][0];
#pragma unroll
        for (int r = 0; r < 4; r++) {
            const int row = quad * 4 + r;   // C/D layout: row = quad*4+reg, col = lane&15
            const float gr = (float)gcur[row * 776 + ob];
            const float gz = (float)gcur[row * 776 + 256 + ob];
            const float gn = (float)gcur[row * 776 + 512 + ob];
            const float rg = sigmoidf_(gr + acc[0][r]);
            const float zg = sigmoidf_(gz + acc[1][r]);
            const float ng = tanhf_(gn + rg * (acc[2][r] + bhhn));
            float h = st[r];
            h = ng + zg * (h - ng);         // (1-z)*n + z*h, fp32 master state
            st[r] = h;
            hxn[row * 264 + ob] = (__bf16)h;
        }
        __syncthreads();   // single barrier: hx visible + gi[t+1] staged (vmcnt drained)
        cur = nxt;
    }

    float* finp = isX ? (hxfin + (long)wg * 16 * 256) : hmfin;
#pragma unroll
    for (int r = 0; r < 4; r++)
        finp[(quad * 4 + r) * 256 + ob] = st[r];
}

// ---------------- K5: cosine gate at t=T-1 -> output ----------------
__global__ void finalize(const float* __restrict__ hxfin, const float* __restrict__ hmfin,
                         const float* __restrict__ W_sx, const float* __restrict__ b_sx,
                         const float* __restrict__ W_sm, const float* __restrict__ b_sm,
                         float* __restrict__ out)
{
    const int b = blockIdx.x;      // 256
    const int lane = threadIdx.x;  // 64
    float qx[4], qm[4];
#pragma unroll
    for (int s = 0; s < 4; s++) {
        float px = 0.f, pm = 0.f;
#pragma unroll
        for (int i = 0; i < 4; i++) {
            int h = i * 64 + lane;
            px += W_sx[s * 256 + h] * hxfin[b * 256 + h];
            pm += W_sm[s * 256 + h] * hmfin[h];
        }
        for (int off = 32; off; off >>= 1) { px += __shfl_xor(px, off); pm += __shfl_xor(pm, off); }
        qx[s] = px + b_sx[s];
        qm[s] = pm + b_sm[s];
    }
    float num = 0.f, nx = 0.f, nm = 0.f;
#pragma unroll
    for (int s = 0; s < 4; s++) { num += qx[s] * qm[s]; nx += qx[s] * qx[s]; nm += qm[s] * qm[s]; }
    const float den = fmaxf(sqrtf(nx), 1e-8f) * fmaxf(sqrtf(nm), 1e-8f);
    const float g = 1.0f / (1.0f + __expf(-num / den));
#pragma unroll
    for (int i = 0; i < 4; i++) {
        int h = i * 64 + lane;
        out[b * 256 + h] = g * hxfin[b * 256 + h] + (1.0f - g) * hmfin[h];
    }
}

extern "C" void kernel_launch(void* const* d_in, const int* in_sizes, int n_in,
                              void* d_out, int out_size, void* d_ws, size_t ws_size,
                              hipStream_t stream)
{
    (void)in_sizes; (void)n_in; (void)out_size; (void)ws_size;
    const float* x      = (const float*)d_in[0];
    const float* W_emb  = (const float*)d_in[1];
    const float* b_emb  = (const float*)d_in[2];
    const float* gamma  = (const float*)d_in[3];
    const float* beta   = (const float*)d_in[4];
    const float* memory = (const float*)d_in[5];
    const float* w_ih_x = (const float*)d_in[6];
    const float* w_hh_x = (const float*)d_in[7];
    const float* b_ih_x = (const float*)d_in[8];
    const float* b_hh_x = (const float*)d_in[9];
    const float* w_ih_m = (const float*)d_in[10];
    const float* w_hh_m = (const float*)d_in[11];
    const float* b_ih_m = (const float*)d_in[12];
    const float* b_hh_m = (const float*)d_in[13];
    const float* W_sx   = (const float*)d_in[14];
    const float* b_sx   = (const float*)d_in[15];
    const float* W_sm   = (const float*)d_in[16];
    const float* b_sm   = (const float*)d_in[17];
    float* out = (float*)d_out;
    char* ws = (char*)d_ws;

    __bf16* xb    = (__bf16*)(ws + OFF_XB);
    __bf16* wembb = (__bf16*)(ws + OFF_WEMB);
    __bf16* whxb  = (__bf16*)(ws + OFF_WHX);
    __bf16* whmb  = (__bf16*)(ws + OFF_WHM);
    float*  sums  = (float*)(ws + OFF_SUM);
    float*  ssqs  = (float*)(ws + OFF_SSQ);
    float*  biasx = (float*)(ws + OFF_BIASX);
    __bf16* gim   = (__bf16*)(ws + OFF_GIM);
    __bf16* eact  = (__bf16*)(ws + OFF_EACT);
    __bf16* gi    = (__bf16*)(ws + OFF_GI);
    float*  hxf   = (float*)(ws + OFF_HXF);
    float*  hmf   = (float*)(ws + OFF_HMF);
    __bf16* wpx   = (__bf16*)(ws + OFF_WPX);

    prep<<<18432, 256, 0, stream>>>(x, W_emb, w_hh_x, w_hh_m, xb, wembb, whxb, whmb, sums);
    gemm_nt<0><<<dim3(256, 8), 256, 0, stream>>>(xb, wembb, b_emb, eact, sums, ssqs, 128, 1024);
    build_wp<<<768, 64, 0, stream>>>(w_ih_x, b_ih_x, b_hh_x, sums, ssqs, gamma, beta, wpx, biasx);
    build_gim<<<dim3(768, 4), 64, 0, stream>>>(memory, w_ih_m, b_ih_m, b_hh_m, gim);
    gemm_nt<1><<<dim3(256, 6), 256, 0, stream>>>(eact, wpx, biasx, gi, sums, ssqs, 1024, 768);
    recurrence<<<17, 1024, 0, stream>>>(gi, gim, whxb, whmb, b_hh_x, b_hh_m, hxf, hmf);
    finalize<<<256, 64, 0, stream>>>(hxf, hmf, W_sx, b_sx, W_sm, b_sm, out);
}

// Round 5
// 490.217 us; speedup vs baseline: 1.0989x; 1.0989x over previous
//
#include <hip/hip_runtime.h>
#include <stdint.h>

// MemoryDiscriminator: embed-GEMM + LeakyReLU + BN(fold into GEMM2) + dual GRU scan + cosine gate.
// Key identities: hm is batch-uniform; only t=T-1 output needed; gi_x hoisted out of scan.
// R5: gi re-laid out [t][b][768]; gemm(gi) + recurrence FUSED into one kernel with per-m-tile
//     flags (agent-scope release/acquire). Recurrence wgs = blockIdx 0..16 (scheduled first,
//     hold 17 CUs, poll); gemm blocks 17.. produce tiles in t-order on the other CUs.
//     82KB LDS forces 1 wg/CU so gemm never cohabits recurrence CUs. Recurrence keeps the
//     R3 8-wave shape (R4's 16-wave doubled redundant LDS A-frag traffic -> regression).

typedef float  f32x4 __attribute__((ext_vector_type(4)));
typedef __bf16 bf16x8 __attribute__((ext_vector_type(8)));

#define B_   256
#define T_   128
#define IN_  128
#define H_   1024
#define OUT_ 256
#define M_   32768   // B*T

// ---------------- workspace layout (bytes) ----------------
static constexpr size_t OFF_XB    = 0;          // 32768*128 bf16   = 8,388,608
static constexpr size_t OFF_WEMB  = 8388608;    // 1024*128 bf16    = 262,144
static constexpr size_t OFF_WHX   = 8650752;    // 768*256 bf16     = 393,216
static constexpr size_t OFF_WHM   = 9043968;    // 768*256 bf16     = 393,216
static constexpr size_t OFF_SUM   = 9437184;    // 1024 f32
static constexpr size_t OFF_SSQ   = 9441280;    // 1024 f32
static constexpr size_t OFF_FLAGS = 9445376;    // 256 int (tile-ready flags, zeroed by prep)
static constexpr size_t OFF_BIASX = 9453568;    // 768 f32 (padded)
static constexpr size_t OFF_GIM   = 9457664;    // 128*768 bf16     = 196,608
static constexpr size_t OFF_EACT  = 9654272;    // 32768*1024 bf16  = 67,108,864
static constexpr size_t OFF_GI    = 76763136;   // 32768*768 bf16 [t][b][768] = 50,331,648
static constexpr size_t OFF_HXF   = 127094784;  // 256*256 f32
static constexpr size_t OFF_HMF   = 127356928;  // 16*256 f32
static constexpr size_t OFF_WPX   = 127373312;  // 768*1024 bf16    = 1,572,864
// total ~128.9 MB

__device__ __forceinline__ float sigmoidf_(float x) {
    return __builtin_amdgcn_rcpf(1.0f + __expf(-x));
}
__device__ __forceinline__ float tanhf_(float x) {
    return 1.0f - 2.0f * __builtin_amdgcn_rcpf(1.0f + __expf(2.0f * x));
}
__device__ __forceinline__ void gload_lds16(const void* g, void* l) {
    __builtin_amdgcn_global_load_lds(
        (const __attribute__((address_space(1))) unsigned int*)g,
        (__attribute__((address_space(3))) unsigned int*)l, 16, 0, 0);
}

// ---------------- K0: fp32->bf16 conversions + zero stats & flags ----------------
__global__ void prep(const float* __restrict__ x, const float* __restrict__ wemb,
                     const float* __restrict__ whx, const float* __restrict__ whm,
                     __bf16* __restrict__ xb, __bf16* __restrict__ wembb,
                     __bf16* __restrict__ whxb, __bf16* __restrict__ whmb,
                     float* __restrict__ stats /*2048*/, int* __restrict__ flags /*256*/)
{
    long i = (long)blockIdx.x * 256 + threadIdx.x;
    if (i < 2048) stats[i] = 0.0f;
    else if (i < 2304) flags[i - 2048] = 0;
    if (i < 4194304)      xb[i] = (__bf16)x[i];
    else if (i < 4325376) wembb[i - 4194304] = (__bf16)wemb[i - 4194304];
    else if (i < 4521984) whxb[i - 4325376]  = (__bf16)whx[i - 4325376];
    else if (i < 4718592) whmb[i - 4521984]  = (__bf16)whm[i - 4521984];
}

// ---------------- K1: eact GEMM (+bias, LeakyReLU, BN stats), 128x128 tile, BK=32 ----------------
__launch_bounds__(256)
__global__ void gemm_e(const __bf16* __restrict__ A, const __bf16* __restrict__ Bm,
                       const float* __restrict__ bias, __bf16* __restrict__ C,
                       float* __restrict__ sums, float* __restrict__ ssqs,
                       int K, int N)
{
    __shared__ __bf16 As[128 * 32];
    __shared__ __bf16 Bs[128 * 32];
    const int tid  = threadIdx.x;
    const int lane = tid & 63;
    const int wv   = tid >> 6;
    const int wm   = wv >> 1, wn = wv & 1;
    const int l15  = lane & 15, quad = lane >> 4;
    const long m0 = (long)blockIdx.x * 128;
    const long n0 = (long)blockIdx.y * 128;

    const int srow = lane >> 2;
    const int scol = (lane & 3) * 8;
    const __bf16* ag[2]; const __bf16* bg[2];
    __bf16* al[2]; __bf16* bl[2];
#pragma unroll
    for (int j = 0; j < 2; j++) {
        const int s = wv * 2 + j;
        ag[j] = A  + (m0 + s * 16 + srow) * K + scol;
        bg[j] = Bm + (n0 + s * 16 + srow) * K + scol;
        al[j] = &As[s * 512];
        bl[j] = &Bs[s * 512];
    }

    const f32x4 fz = {0.f, 0.f, 0.f, 0.f};
    f32x4 acc[4][4];
#pragma unroll
    for (int i = 0; i < 4; i++)
#pragma unroll
        for (int j = 0; j < 4; j++) acc[i][j] = fz;

    for (int k0 = 0; k0 < K; k0 += 32) {
        __syncthreads();
        gload_lds16(ag[0] + k0, al[0]);
        gload_lds16(ag[1] + k0, al[1]);
        gload_lds16(bg[0] + k0, bl[0]);
        gload_lds16(bg[1] + k0, bl[1]);
        __syncthreads();
        bf16x8 af[4], bfr[4];
#pragma unroll
        for (int mt = 0; mt < 4; mt++)
            af[mt] = *(const bf16x8*)(&As[(wm * 64 + mt * 16 + l15) * 32 + quad * 8]);
#pragma unroll
        for (int nt = 0; nt < 4; nt++)
            bfr[nt] = *(const bf16x8*)(&Bs[(wn * 64 + nt * 16 + l15) * 32 + quad * 8]);
#pragma unroll
        for (int mt = 0; mt < 4; mt++)
#pragma unroll
            for (int nt = 0; nt < 4; nt++)
                acc[mt][nt] = __builtin_amdgcn_mfma_f32_16x16x32_bf16(af[mt], bfr[nt], acc[mt][nt], 0, 0, 0);
    }

#pragma unroll
    for (int nt = 0; nt < 4; nt++) {
        const long ncol = n0 + wn * 64 + nt * 16 + l15;
        const float bi = bias[ncol];
        float s = 0.f, ss = 0.f;
#pragma unroll
        for (int mt = 0; mt < 4; mt++) {
#pragma unroll
            for (int r = 0; r < 4; r++) {
                float v = acc[mt][nt][r] + bi;
                v = (v >= 0.f) ? v : 0.2f * v;
                __bf16 hv = (__bf16)v;
                C[(m0 + wm * 64 + mt * 16 + quad * 4 + r) * (long)N + ncol] = hv;
                float fv = (float)hv; s += fv; ss += fv * fv;
            }
        }
        s += __shfl_xor(s, 16);  ss += __shfl_xor(ss, 16);
        s += __shfl_xor(s, 32);  ss += __shfl_xor(ss, 32);
        if (lane < 16) {
            atomicAdd(&sums[n0 + wn * 64 + nt * 16 + lane], s);
            atomicAdd(&ssqs[n0 + wn * 64 + nt * 16 + lane], ss);
        }
    }
}

// ---------------- K2: build_wp (blocks 0..767) + build_gim (blocks 768..3839) merged ----------------
__global__ void build_misc(const float* __restrict__ w_ih_x, const float* __restrict__ b_ih_x,
                           const float* __restrict__ b_hh_x, const float* __restrict__ sums,
                           const float* __restrict__ ssqs, const float* __restrict__ gamma,
                           const float* __restrict__ beta, __bf16* __restrict__ wpx,
                           float* __restrict__ biasx,
                           const float* __restrict__ memory, const float* __restrict__ w_ih_m,
                           const float* __restrict__ b_ih_m, const float* __restrict__ b_hh_m,
                           __bf16* __restrict__ gim)
{
    const int lane = threadIdx.x;  // 64
    if (blockIdx.x < 768) {
        const int j = blockIdx.x;
        const float inv = 1.0f / 32768.0f;
        float accv = 0.f;
#pragma unroll
        for (int i = 0; i < 16; i++) {
            int h = i * 64 + lane;
            float mean = sums[h] * inv;
            float var  = ssqs[h] * inv - mean * mean;
            float s    = rsqrtf(var + 1e-5f) * gamma[h];
            float c    = beta[h] - mean * s;
            float w = w_ih_x[(long)j * 1024 + h];
            wpx[(long)j * 1024 + h] = (__bf16)(w * s);
            accv += c * w;
        }
        for (int off = 32; off; off >>= 1) accv += __shfl_xor(accv, off);
        if (lane == 0) biasx[j] = accv + b_ih_x[j] + (j < 512 ? b_hh_x[j] : 0.0f);
    } else {
        const int g = blockIdx.x - 768;
        const int j = g & 1023 % 1024;  // placeholder, fixed below
        const int jj = g % 768;
        const int t0 = (g / 768) * 32;
        float w[16];
#pragma unroll
        for (int i = 0; i < 16; i++) w[i] = w_ih_m[(long)jj * 1024 + i * 64 + lane];
        const float bb = b_ih_m[jj] + (jj < 512 ? b_hh_m[jj] : 0.0f);
        for (int t = t0; t < t0 + 32; t++) {
            float s = 0.f;
#pragma unroll
            for (int i = 0; i < 16; i++) s += w[i] * memory[(long)t * 1024 + i * 64 + lane];
            for (int off = 32; off; off >>= 1) s += __shfl_xor(s, off);
            if (lane == 0) gim[t * 768 + jj] = (__bf16)(s + bb);
        }
        (void)j;
    }
}

// ---------------- K3: FUSED gi-GEMM producer + GRU recurrence consumer ----------------
// blockIdx 0..16: recurrence (wg<16: 16 batch rows; wg16: hm). blockIdx 17..1552: gemm tiles,
// g = bx-17, mt = g/6 (t-order!), nt = g%6. gi layout: [t][b][768], row m = t*256+b.
// 82KB LDS -> 1 wg/CU everywhere (gemm never slows the 17 recurrence CUs).
__launch_bounds__(512, 2)
__global__ void fused(const __bf16* __restrict__ eact, const __bf16* __restrict__ wpx,
                      const float* __restrict__ biasx, __bf16* __restrict__ gi,
                      const __bf16* __restrict__ gim,
                      const __bf16* __restrict__ whx, const __bf16* __restrict__ whm,
                      const float* __restrict__ bhhx, const float* __restrict__ bhhm,
                      float* __restrict__ hxfin, float* __restrict__ hmfin,
                      int* __restrict__ flags)
{
    __shared__ union {
        struct { __bf16 hxl[2][16 * 264]; __bf16 gil[2][16 * 776]; } rec;  // 66,560 B
        struct { __bf16 As[128 * 32]; __bf16 Bs[128 * 32]; } gm;           // 16,384 B
        char pad[83968];                                                    // force 1 wg/CU
    } sm;

    const int tid  = threadIdx.x;
    const int lane = tid & 63;
    const int v    = tid >> 6;     // wave 0..7
    const int l15  = lane & 15, quad = lane >> 4;

    if (blockIdx.x >= 17) {
        // ---------------- producer: one 128x128 tile of gi ----------------
        const int g  = blockIdx.x - 17;
        const int mt = g / 6;
        const long m0 = (long)mt * 128;
        const long n0 = (long)(g % 6) * 128;
        const int wm = v >> 1, wn = v & 1;   // wave tile: 32 rows x 64 cols

        const int srow = lane >> 2;
        const int scol = (lane & 3) * 8;
        // A row m -> eact[(b= m&255)][(t= m>>8)]
        const long m = m0 + v * 16 + srow;
        const __bf16* agA = eact + (((m & 255) << 7) + (m >> 8)) * 1024 + scol;
        const __bf16* agB = wpx + (n0 + v * 16 + srow) * 1024 + scol;
        __bf16* alA = &sm.gm.As[v * 512];
        __bf16* alB = &sm.gm.Bs[v * 512];

        const f32x4 fz = {0.f, 0.f, 0.f, 0.f};
        f32x4 acc[2][4];
#pragma unroll
        for (int i = 0; i < 2; i++)
#pragma unroll
            for (int j = 0; j < 4; j++) acc[i][j] = fz;

        for (int k0 = 0; k0 < 1024; k0 += 32) {
            __syncthreads();
            gload_lds16(agA + k0, alA);
            gload_lds16(agB + k0, alB);
            __syncthreads();
            bf16x8 af[2], bfr[4];
#pragma unroll
            for (int i = 0; i < 2; i++)
                af[i] = *(const bf16x8*)(&sm.gm.As[(wm * 32 + i * 16 + l15) * 32 + quad * 8]);
#pragma unroll
            for (int j = 0; j < 4; j++)
                bfr[j] = *(const bf16x8*)(&sm.gm.Bs[(wn * 64 + j * 16 + l15) * 32 + quad * 8]);
#pragma unroll
            for (int i = 0; i < 2; i++)
#pragma unroll
                for (int j = 0; j < 4; j++)
                    acc[i][j] = __builtin_amdgcn_mfma_f32_16x16x32_bf16(af[i], bfr[j], acc[i][j], 0, 0, 0);
        }

#pragma unroll
        for (int j = 0; j < 4; j++) {
            const long ncol = n0 + wn * 64 + j * 16 + l15;
            const float bi = biasx[ncol];
#pragma unroll
            for (int i = 0; i < 2; i++)
#pragma unroll
                for (int r = 0; r < 4; r++)
                    gi[(m0 + wm * 32 + i * 16 + quad * 4 + r) * 768 + ncol] =
                        (__bf16)(acc[i][j][r] + bi);
        }
        __syncthreads();   // all waves' stores drained (vmcnt0 at barrier)
        if (tid == 0)
            __hip_atomic_fetch_add(&flags[mt], 1, __ATOMIC_RELEASE, __HIP_MEMORY_SCOPE_AGENT);
        return;
    }

    // ---------------- consumer: GRU recurrence (R3 8-wave shape) ----------------
    const int wg   = blockIdx.x;   // 0..16
    const bool isX = (wg < 16);
    const __bf16* wh    = isX ? whx : whm;
    const float*  bhh   = isX ? bhhx : bhhm;
    const __bf16* gbase = isX ? gi : gim;

    bf16x8 W[6][8];
#pragma unroll
    for (int nt = 0; nt < 6; nt++) {
        const int gg = nt >> 1, ct = nt & 1;
        const long j = gg * 256 + (v * 2 + ct) * 16 + l15;
#pragma unroll
        for (int kt = 0; kt < 8; kt++)
            W[nt][kt] = *(const bf16x8*)(wh + j * 256 + kt * 32 + quad * 8);
    }
    float bhhn[2];
#pragma unroll
    for (int ct = 0; ct < 2; ct++) bhhn[ct] = bhh[512 + v * 32 + ct * 16 + l15];

    for (int i = tid; i < 16 * 264; i += 512) sm.rec.hxl[0][i] = (__bf16)0.f;

    float st[8];
#pragma unroll
    for (int i = 0; i < 8; i++) st[i] = 0.f;

    const int r0 = v * 2, r1 = r0 + 1;
    // gi[t][b][768]: addr(t, b) = (t*256 + b)*768 ; hm wg reads gim[t*768]
    const long base0 = isX ? (long)(wg * 16 + r0) * 768 : 0;
    const long base1 = isX ? (long)(wg * 16 + r1) * 768 : 0;
    const long tstr  = isX ? (long)256 * 768 : 768;
    const int  myhalf = wg >> 3;   // 0 or 1 (which 128-row half of each t-pair of tiles)

    int ready = -1;
    // wait for tile of t=0, then prefetch gi[0] -> gil[0]
    if (isX) {
        const int need = myhalf;
        if (__hip_atomic_load(&flags[need], __ATOMIC_ACQUIRE, __HIP_MEMORY_SCOPE_AGENT) == 6) ready = need;
        else {
            while (__hip_atomic_load(&flags[need], __ATOMIC_ACQUIRE, __HIP_MEMORY_SCOPE_AGENT) != 6)
                __builtin_amdgcn_s_sleep(2);
            ready = need;
        }
    }
    {
        const __bf16* p0 = gbase + base0;
        const __bf16* p1 = gbase + base1;
        gload_lds16(p0 + (long)lane * 8, &sm.rec.gil[0][r0 * 776]);
        gload_lds16(p1 + (long)lane * 8, &sm.rec.gil[0][r1 * 776]);
        if (lane < 32) {
            gload_lds16(p0 + 512 + (long)lane * 8, &sm.rec.gil[0][r0 * 776 + 512]);
            gload_lds16(p1 + 512 + (long)lane * 8, &sm.rec.gil[0][r1 * 776 + 512]);
        }
    }
    __syncthreads();

    int cur = 0;
    for (int t = 0; t < 128; t++) {
        if (t < 127) {
            if (isX) {
                const int need = 2 * (t + 1) + myhalf;
                if (need > ready) {
                    int probe = need + 14; if (probe > 255) probe = 255;
                    if (__hip_atomic_load(&flags[probe], __ATOMIC_ACQUIRE, __HIP_MEMORY_SCOPE_AGENT) == 6)
                        ready = probe;
                    else {
                        while (__hip_atomic_load(&flags[need], __ATOMIC_ACQUIRE, __HIP_MEMORY_SCOPE_AGENT) != 6)
                            __builtin_amdgcn_s_sleep(2);
                        ready = need;
                    }
                }
            }
            const __bf16* p0 = gbase + base0 + (long)(t + 1) * tstr;
            const __bf16* p1 = gbase + base1 + (long)(t + 1) * tstr;
            __bf16* dst = &sm.rec.gil[(t + 1) & 1][0];
            gload_lds16(p0 + (long)lane * 8, dst + r0 * 776);
            gload_lds16(p1 + (long)lane * 8, dst + r1 * 776);
            if (lane < 32) {
                gload_lds16(p0 + 512 + (long)lane * 8, dst + r0 * 776 + 512);
                gload_lds16(p1 + 512 + (long)lane * 8, dst + r1 * 776 + 512);
            }
        }

        const f32x4 fz = {0.f, 0.f, 0.f, 0.f};
        f32x4 acc[6];
#pragma unroll
        for (int nt = 0; nt < 6; nt++) acc[nt] = fz;
        const __bf16* hxc = &sm.rec.hxl[cur][0];
#pragma unroll
        for (int kt = 0; kt < 8; kt++) {
            bf16x8 a = *(const bf16x8*)(hxc + l15 * 264 + kt * 32 + quad * 8);
#pragma unroll
            for (int nt = 0; nt < 6; nt++)
                acc[nt] = __builtin_amdgcn_mfma_f32_16x16x32_bf16(a, W[nt][kt], acc[nt], 0, 0, 0);
        }

        const int nxt = cur ^ 1;
        __bf16* hxn = &sm.rec.hxl[nxt][0];
        const __bf16* gcur = &sm.rec.gil[t & 1][0];
#pragma unroll
        for (int ct = 0; ct < 2; ct++) {
            const int ob = v * 32 + ct * 16 + l15;
#pragma unroll
            for (int r = 0; r < 4; r++) {
                const int row = quad * 4 + r;   // C/D: row = quad*4+reg, col = lane&15
                const float gr = (float)gcur[row * 776 + ob];
                const float gz = (float)gcur[row * 776 + 256 + ob];
                const float gn = (float)gcur[row * 776 + 512 + ob];
                const float rg = sigmoidf_(gr + acc[ct][r]);
                const float zg = sigmoidf_(gz + acc[2 + ct][r]);
                const float ng = tanhf_(gn + rg * (acc[4 + ct][r] + bhhn[ct]));
                float h = st[ct * 4 + r];
                h = ng + zg * (h - ng);
                st[ct * 4 + r] = h;
                hxn[row * 264 + ob] = (__bf16)h;
            }
        }
        __syncthreads();
        cur = nxt;
    }

    float* finp = isX ? (hxfin + (long)wg * 16 * 256) : hmfin;
#pragma unroll
    for (int ct = 0; ct < 2; ct++) {
        const int ob = v * 32 + ct * 16 + l15;
#pragma unroll
        for (int r = 0; r < 4; r++)
            finp[(quad * 4 + r) * 256 + ob] = st[ct * 4 + r];
    }
}

// ---------------- K4: cosine gate at t=T-1 -> output ----------------
__global__ void finalize(const float* __restrict__ hxfin, const float* __restrict__ hmfin,
                         const float* __restrict__ W_sx, const float* __restrict__ b_sx,
                         const float* __restrict__ W_sm, const float* __restrict__ b_sm,
                         float* __restrict__ out)
{
    const int b = blockIdx.x;      // 256
    const int lane = threadIdx.x;  // 64
    float qx[4], qm[4];
#pragma unroll
    for (int s = 0; s < 4; s++) {
        float px = 0.f, pm = 0.f;
#pragma unroll
        for (int i = 0; i < 4; i++) {
            int h = i * 64 + lane;
            px += W_sx[s * 256 + h] * hxfin[b * 256 + h];
            pm += W_sm[s * 256 + h] * hmfin[h];
        }
        for (int off = 32; off; off >>= 1) { px += __shfl_xor(px, off); pm += __shfl_xor(pm, off); }
        qx[s] = px + b_sx[s];
        qm[s] = pm + b_sm[s];
    }
    float num = 0.f, nx = 0.f, nm = 0.f;
#pragma unroll
    for (int s = 0; s < 4; s++) { num += qx[s] * qm[s]; nx += qx[s] * qx[s]; nm += qm[s] * qm[s]; }
    const float den = fmaxf(sqrtf(nx), 1e-8f) * fmaxf(sqrtf(nm), 1e-8f);
    const float g = 1.0f / (1.0f + __expf(-num / den));
#pragma unroll
    for (int i = 0; i < 4; i++) {
        int h = i * 64 + lane;
        out[b * 256 + h] = g * hxfin[b * 256 + h] + (1.0f - g) * hmfin[h];
    }
}

extern "C" void kernel_launch(void* const* d_in, const int* in_sizes, int n_in,
                              void* d_out, int out_size, void* d_ws, size_t ws_size,
                              hipStream_t stream)
{
    (void)in_sizes; (void)n_in; (void)out_size; (void)ws_size;
    const float* x      = (const float*)d_in[0];
    const float* W_emb  = (const float*)d_in[1];
    const float* b_emb  = (const float*)d_in[2];
    const float* gamma  = (const float*)d_in[3];
    const float* beta   = (const float*)d_in[4];
    const float* memory = (const float*)d_in[5];
    const float* w_ih_x = (const float*)d_in[6];
    const float* w_hh_x = (const float*)d_in[7];
    const float* b_ih_x = (const float*)d_in[8];
    const float* b_hh_x = (const float*)d_in[9];
    const float* w_ih_m = (const float*)d_in[10];
    const float* w_hh_m = (const float*)d_in[11];
    const float* b_ih_m = (const float*)d_in[12];
    const float* b_hh_m = (const float*)d_in[13];
    const float* W_sx   = (const float*)d_in[14];
    const float* b_sx   = (const float*)d_in[15];
    const float* W_sm   = (const float*)d_in[16];
    const float* b_sm   = (const float*)d_in[17];
    float* out = (float*)d_out;
    char* ws = (char*)d_ws;

    __bf16* xb    = (__bf16*)(ws + OFF_XB);
    __bf16* wembb = (__bf16*)(ws + OFF_WEMB);
    __bf16* whxb  = (__bf16*)(ws + OFF_WHX);
    __bf16* whmb  = (__bf16*)(ws + OFF_WHM);
    float*  sums  = (float*)(ws + OFF_SUM);
    float*  ssqs  = (float*)(ws + OFF_SSQ);
    int*    flags = (int*)(ws + OFF_FLAGS);
    float*  biasx = (float*)(ws + OFF_BIASX);
    __bf16* gim   = (__bf16*)(ws + OFF_GIM);
    __bf16* eact  = (__bf16*)(ws + OFF_EACT);
    __bf16* gi    = (__bf16*)(ws + OFF_GI);
    float*  hxf   = (float*)(ws + OFF_HXF);
    float*  hmf   = (float*)(ws + OFF_HMF);
    __bf16* wpx   = (__bf16*)(ws + OFF_WPX);

    prep<<<18432, 256, 0, stream>>>(x, W_emb, w_hh_x, w_hh_m, xb, wembb, whxb, whmb, sums, flags);
    gemm_e<<<dim3(256, 8), 256, 0, stream>>>(xb, wembb, b_emb, eact, sums, ssqs, 128, 1024);
    build_misc<<<3840, 64, 0, stream>>>(w_ih_x, b_ih_x, b_hh_x, sums, ssqs, gamma, beta, wpx, biasx,
                                        memory, w_ih_m, b_ih_m, b_hh_m, gim);
    fused<<<17 + 1536, 512, 0, stream>>>(eact, wpx, biasx, gi, gim, whxb, whmb,
                                         b_hh_x, b_hh_m, hxf, hmf, flags);
    finalize<<<256, 64, 0, stream>>>(hxf, hmf, W_sx, b_sx, W_sm, b_sm, out);
}